// Round 1
// baseline (333.020 us; speedup 1.0000x reference)
//
#include <hip/hip_runtime.h>

#define N_NODES 100000
#define E_EDGES 1600000
#define DIM     128

// Workspace layout (bytes), total ~70.9 MiB:
#define HB_OFF    0            // h packed bf16: N*64 u32 = 25,600,000
#define AGGB_OFF  25600000     // mean-agg packed bf16: N*64 u32 = 25,600,000
#define WTB_OFF   51200000     // WcatT bf16 B-fragment layout: 16384 u32 = 65,536
#define DEG8_OFF  51265536     // 8 XCD-private histograms: 8*N int = 3,200,000
#define OFFS_OFF  54465536     // N+1 int (padded)
#define BSUM_OFF  54865600     // 98 int (padded)
#define OFFSX_OFF 54866112     // per-slice start: 8*N int = 3,200,000
#define SRC_OFF   58066112     // E int = 6,400,000
#define RANK_OFF  64466112     // E int = 6,400,000 -> end 70,866,112

#define SCAN_BLOCKS 98

typedef __attribute__((ext_vector_type(8))) short short8;
typedef __attribute__((ext_vector_type(4))) float floatx4;

// ---------- bf16 pack/unpack (RNE) ----------
__device__ __forceinline__ unsigned bf16pack(float a, float b) {
  unsigned ua = __float_as_uint(a); ua += 0x7fffu + ((ua >> 16) & 1u);
  unsigned ub = __float_as_uint(b); ub += 0x7fffu + ((ub >> 16) & 1u);
  return (ua >> 16) | (ub & 0xffff0000u);
}
__device__ __forceinline__ float2 bf16unpack(unsigned p) {
  return make_float2(__uint_as_float(p << 16), __uint_as_float(p & 0xffff0000u));
}

// ------------- prep: LayerNorm+ReLU -> hb, XCD-private degree+rank, W pack ---
__global__ __launch_bounds__(256) void k_prep(const float* __restrict__ x,
                                              const float* __restrict__ lw,
                                              const float* __restrict__ lb,
                                              const float* __restrict__ Wl,
                                              const float* __restrict__ Wr,
                                              const int* __restrict__ ei,
                                              unsigned* __restrict__ hb,
                                              int* __restrict__ deg8,
                                              int* __restrict__ rank,
                                              unsigned* __restrict__ wtb) {
  int gid = blockIdx.x * 256 + threadIdx.x;

  // --- LN+ReLU ---
  {
    int row  = blockIdx.x * 4 + (threadIdx.x >> 6);
    int lane = threadIdx.x & 63;
    float2 v = ((const float2*)(x + (size_t)row * DIM))[lane];
    float s  = v.x + v.y;
    float sq = v.x * v.x + v.y * v.y;
    #pragma unroll
    for (int off = 32; off > 0; off >>= 1) {
      s  += __shfl_xor(s, off);
      sq += __shfl_xor(sq, off);
    }
    float mu  = s * (1.0f / 128.0f);
    float var = sq * (1.0f / 128.0f) - mu * mu;
    float rs  = rsqrtf(var + 1e-5f);
    float2 w = ((const float2*)lw)[lane];
    float2 b = ((const float2*)lb)[lane];
    float ox = fmaxf((v.x - mu) * rs * w.x + b.x, 0.0f);
    float oy = fmaxf((v.y - mu) * rs * w.y + b.y, 0.0f);
    hb[(size_t)row * 64 + lane] = bf16pack(ox, oy);
  }

  // --- XCD-private degree histogram + per-edge (slice,rank) ---
  // Atomics stay homed in the issuing XCD's L2: no cross-XCD line ping-pong.
  if (gid < E_EDGES / 4) {
    int sl;
    asm("s_getreg_b32 %0, hwreg(HW_REG_XCC_ID)" : "=s"(sl));
    sl &= 7;
    int* degs = deg8 + sl * N_NODES;
    int tag = sl << 28;
    int4 d = ((const int4*)(ei + E_EDGES))[gid];
    int4 r;
    r.x = atomicAdd(&degs[d.x], 1) | tag;
    r.y = atomicAdd(&degs[d.y], 1) | tag;
    r.z = atomicAdd(&degs[d.z], 1) | tag;
    r.w = atomicAdd(&degs[d.w], 1) | tag;
    ((int4*)rank)[gid] = r;
  }

  // --- weight pack (bf16, B-fragment layout) ---
  if (gid < 16384) {
    int j2 = gid & 3;
    int q  = (gid >> 2) & 3;
    int c  = (gid >> 4) & 127;
    int kb = gid >> 11;
    int k0 = kb * 32 + q * 8 + j2 * 2;
    int k1 = k0 + 1;
    float v0 = (k0 < 128) ? Wl[c * 128 + k0] : Wr[c * 128 + (k0 - 128)];
    float v1 = (k1 < 128) ? Wl[c * 128 + k1] : Wr[c * 128 + (k1 - 128)];
    wtb[gid] = bf16pack(v0, v1);
  }
}

// ---------------- scan stage 1: per-block exclusive scan (1024 nodes) --------
// Sums the 8 XCD-private slices per node on the fly.
__global__ __launch_bounds__(256) void k_scan1(const int* __restrict__ deg8,
                                               int* __restrict__ offs,
                                               int* __restrict__ bsum) {
  __shared__ int s[256];
  int t = threadIdx.x;
  int base = blockIdx.x * 1024 + t * 4;
  int a0 = 0, a1 = 0, a2 = 0, a3 = 0;
  #pragma unroll
  for (int xs = 0; xs < 8; ++xs) {
    const int* dx = deg8 + xs * N_NODES;
    if (base + 0 < N_NODES) a0 += dx[base + 0];
    if (base + 1 < N_NODES) a1 += dx[base + 1];
    if (base + 2 < N_NODES) a2 += dx[base + 2];
    if (base + 3 < N_NODES) a3 += dx[base + 3];
  }
  s[t] = a0 + a1 + a2 + a3;
  __syncthreads();
  #pragma unroll
  for (int off = 1; off < 256; off <<= 1) {
    int x = (t >= off) ? s[t - off] : 0;
    __syncthreads();
    s[t] += x;
    __syncthreads();
  }
  int excl = (t > 0) ? s[t - 1] : 0;
  if (t == 255) bsum[blockIdx.x] = s[255];
  if (base + 0 < N_NODES) offs[base + 0] = excl;
  if (base + 1 < N_NODES) offs[base + 1] = excl + a0;
  if (base + 2 < N_NODES) offs[base + 2] = excl + a0 + a1;
  if (base + 3 < N_NODES) offs[base + 3] = excl + a0 + a1 + a2;
}

// -------- scan stage 2+3 fused + per-slice start table (offsx) ---------------
__global__ __launch_bounds__(256) void k_scan23(int* __restrict__ offs,
                                                const int* __restrict__ bsum,
                                                const int* __restrict__ deg8,
                                                int* __restrict__ offsx) {
  __shared__ int s[128];
  int t = threadIdx.x;
  if (t < 128) s[t] = (t < SCAN_BLOCKS) ? bsum[t] : 0;
  __syncthreads();
  if (t < 128) {
    #pragma unroll
    for (int off = 1; off < 128; off <<= 1) {
      int x = (t >= off) ? s[t - off] : 0;
      __syncthreads();
      s[t] += x;
      __syncthreads();
    }
  } else {
    #pragma unroll
    for (int off = 1; off < 128; off <<= 1) { __syncthreads(); __syncthreads(); }
  }
  int blk = blockIdx.x;
  int base = (blk > 0) ? s[blk - 1] : 0;
  #pragma unroll
  for (int u = 0; u < 4; ++u) {
    int i = blk * 1024 + t * 4 + u;
    if (i < N_NODES) {
      int o = offs[i] + base;
      offs[i] = o;
      int run = o;
      #pragma unroll
      for (int xs = 0; xs < 8; ++xs) {
        offsx[xs * N_NODES + i] = run;
        run += deg8[xs * N_NODES + i];
      }
    }
    if (i == N_NODES) offs[N_NODES] = E_EDGES;
  }
}

// ---------------- CSR fill: atomic-free via (slice,rank) ---------------------
__global__ __launch_bounds__(256) void k_fill(const int* __restrict__ ei,
                                              const int* __restrict__ offsx,
                                              const int* __restrict__ rank,
                                              int* __restrict__ srcidx) {
  int i = blockIdx.x * 256 + threadIdx.x;
  if (i >= E_EDGES / 4) return;
  int4 sv = ((const int4*)ei)[i];
  int4 d = ((const int4*)(ei + E_EDGES))[i];
  int4 r = ((const int4*)rank)[i];
  srcidx[offsx[((r.x >> 28) & 7) * N_NODES + d.x] + (r.x & 0x0FFFFFFF)] = sv.x;
  srcidx[offsx[((r.y >> 28) & 7) * N_NODES + d.y] + (r.y & 0x0FFFFFFF)] = sv.y;
  srcidx[offsx[((r.z >> 28) & 7) * N_NODES + d.z] + (r.z & 0x0FFFFFFF)] = sv.z;
  srcidx[offsx[((r.w >> 28) & 7) * N_NODES + d.w] + (r.w & 0x0FFFFFFF)] = sv.w;
}

// ---------------- gather + mean -> aggb (bf16) -------------------------------
// TWO nodes per wave with interleaved load chains -> 16 outstanding 256B row
// loads per wave. Still 50K independent waves (TLP matters).
__global__ __launch_bounds__(256) void k_gather(const unsigned* __restrict__ hb,
                                                const int* __restrict__ offs,
                                                const int* __restrict__ srcidx,
                                                unsigned* __restrict__ aggb) {
  int wave = threadIdx.x >> 6;
  int lane = threadIdx.x & 63;
  int n0 = blockIdx.x * 8 + wave * 2;
  int n1 = n0 + 1;
  int b0 = __builtin_amdgcn_readfirstlane(offs[n0]);
  int e0 = __builtin_amdgcn_readfirstlane(offs[n0 + 1]);
  int b1 = __builtin_amdgcn_readfirstlane(offs[n1]);
  int e1 = __builtin_amdgcn_readfirstlane(offs[n1 + 1]);
  int m0 = e0 - b0, m1 = e1 - b1;
  int c  = (m0 < m1 ? m0 : m1) & ~7;   // common interleaved part

  float ax0 = 0.0f, ay0 = 0.0f, ax1 = 0.0f, ay1 = 0.0f;

  // interleaved: 16 outstanding loads (8 per chain)
  for (int j = 0; j < c; j += 8) {
    unsigned p0[8], p1[8];
    #pragma unroll
    for (int i = 0; i < 8; ++i) {
      int s0 = srcidx[b0 + j + i];
      int s1 = srcidx[b1 + j + i];
      p0[i] = hb[(size_t)s0 * 64 + lane];
      p1[i] = hb[(size_t)s1 * 64 + lane];
    }
    #pragma unroll
    for (int i = 0; i < 8; ++i) {
      float2 v0 = bf16unpack(p0[i]);
      float2 v1 = bf16unpack(p1[i]);
      ax0 += v0.x; ay0 += v0.y;
      ax1 += v1.x; ay1 += v1.y;
    }
  }
  // tail of node 0
  for (int j = b0 + c; j < e0; ) {
    int rem = e0 - j;
    if (rem >= 8) {
      unsigned p[8];
      #pragma unroll
      for (int i = 0; i < 8; ++i) p[i] = hb[(size_t)srcidx[j + i] * 64 + lane];
      #pragma unroll
      for (int i = 0; i < 8; ++i) { float2 v = bf16unpack(p[i]); ax0 += v.x; ay0 += v.y; }
      j += 8;
    } else {
      float2 v = bf16unpack(hb[(size_t)srcidx[j] * 64 + lane]);
      ax0 += v.x; ay0 += v.y;
      ++j;
    }
  }
  // tail of node 1
  for (int j = b1 + c; j < e1; ) {
    int rem = e1 - j;
    if (rem >= 8) {
      unsigned p[8];
      #pragma unroll
      for (int i = 0; i < 8; ++i) p[i] = hb[(size_t)srcidx[j + i] * 64 + lane];
      #pragma unroll
      for (int i = 0; i < 8; ++i) { float2 v = bf16unpack(p[i]); ax1 += v.x; ay1 += v.y; }
      j += 8;
    } else {
      float2 v = bf16unpack(hb[(size_t)srcidx[j] * 64 + lane]);
      ax1 += v.x; ay1 += v.y;
      ++j;
    }
  }

  float inv0 = 1.0f / fmaxf((float)m0, 1.0f);
  float inv1 = 1.0f / fmaxf((float)m1, 1.0f);
  aggb[(size_t)n0 * 64 + lane] = bf16pack(ax0 * inv0, ay0 * inv0);
  aggb[(size_t)n1 * 64 + lane] = bf16pack(ax1 * inv1, ay1 * inv1);
}

// ---------------- bf16 MFMA GEMM: out = [aggb|hb] @ WcatT^T + b_l ------------
__global__ __launch_bounds__(256) void k_gemm(const unsigned* __restrict__ aggb,
                                              const unsigned* __restrict__ hb,
                                              const unsigned* __restrict__ wtb,
                                              const float* __restrict__ bl,
                                              float* __restrict__ out) {
  int wave = threadIdx.x >> 6;
  int lane = threadIdx.x & 63;
  int m = lane & 15;
  int q = lane >> 4;
  int r0 = blockIdx.x * 64 + wave * 16;
  int rowA = r0 + m;
  if (rowA > N_NODES - 1) rowA = N_NODES - 1;  // tail clamp (stores guarded)

  const uint4* ar = (const uint4*)(aggb + (size_t)rowA * 64);
  const uint4* hr = (const uint4*)(hb + (size_t)rowA * 64);
  short8 afrag[8];
  #pragma unroll
  for (int kb = 0; kb < 4; ++kb) {
    uint4 u = ar[kb * 4 + q];
    afrag[kb] = *(short8*)&u;
  }
  #pragma unroll
  for (int kb = 0; kb < 4; ++kb) {
    uint4 u = hr[kb * 4 + q];
    afrag[kb + 4] = *(short8*)&u;
  }

  const uint4* b4 = (const uint4*)wtb;
  #pragma unroll
  for (int ct = 0; ct < 8; ++ct) {
    int c = ct * 16 + m;
    floatx4 acc = {0.0f, 0.0f, 0.0f, 0.0f};
    #pragma unroll
    for (int kb = 0; kb < 8; ++kb) {
      uint4 u = b4[kb * 512 + c * 4 + q];
      short8 bfrag = *(short8*)&u;
      acc = __builtin_amdgcn_mfma_f32_16x16x32_bf16(afrag[kb], bfrag, acc, 0, 0, 0);
    }
    float bias = bl[c];
    #pragma unroll
    for (int reg = 0; reg < 4; ++reg) {
      int r = r0 + q * 4 + reg;
      if (r < N_NODES) out[(size_t)r * DIM + c] = acc[reg] + bias;
    }
  }
}

extern "C" void kernel_launch(void* const* d_in, const int* in_sizes, int n_in,
                              void* d_out, int out_size, void* d_ws, size_t ws_size,
                              hipStream_t stream) {
  const float* x  = (const float*)d_in[0];
  const int*   ei = (const int*)d_in[1];   // [2, E] int32
  const float* lw = (const float*)d_in[2];
  const float* lb = (const float*)d_in[3];
  const float* Wl = (const float*)d_in[4];
  const float* bl = (const float*)d_in[5];
  const float* Wr = (const float*)d_in[6];
  float* out = (float*)d_out;

  char* ws = (char*)d_ws;
  unsigned* hb     = (unsigned*)(ws + HB_OFF);
  unsigned* aggb   = (unsigned*)(ws + AGGB_OFF);
  unsigned* wtb    = (unsigned*)(ws + WTB_OFF);
  int*      deg8   = (int*)(ws + DEG8_OFF);
  int*      offs   = (int*)(ws + OFFS_OFF);
  int*      bsum   = (int*)(ws + BSUM_OFF);
  int*      offsx  = (int*)(ws + OFFSX_OFF);
  int*      srcidx = (int*)(ws + SRC_OFF);
  int*      rank   = (int*)(ws + RANK_OFF);

  hipMemsetAsync(deg8, 0, (size_t)8 * N_NODES * 4, stream);

  k_prep<<<N_NODES / 4, 256, 0, stream>>>(x, lw, lb, Wl, Wr, ei, hb, deg8, rank, wtb);
  k_scan1<<<SCAN_BLOCKS, 256, 0, stream>>>(deg8, offs, bsum);
  k_scan23<<<SCAN_BLOCKS, 256, 0, stream>>>(offs, bsum, deg8, offsx);
  k_fill<<<(E_EDGES / 4 + 255) / 256, 256, 0, stream>>>(ei, offsx, rank, srcidx);
  k_gather<<<N_NODES / 8, 256, 0, stream>>>(hb, offs, srcidx, aggb);
  k_gemm<<<(N_NODES + 63) / 64, 256, 0, stream>>>(aggb, hb, wtb, bl, out);
}

// Round 2
// 265.769 us; speedup vs baseline: 1.2530x; 1.2530x over previous
//
#include <hip/hip_runtime.h>

#define N_NODES 100000
#define E_EDGES 1600000
#define DIM     128

// Binning geometry: coarse bucket = 256 nodes (dst>>8), 391 real buckets, pad 512.
#define NB1     391            // level-1 chunks/blocks (ceil(E/4096)), also blocks in scatter
#define NBINS   512            // padded bucket count (actual 391)
#define NBH     (NBINS * NB1)  // 200192 (bin-major [bin][block] histogram entries)
#define HS_BLOCKS 196          // ceil(NBH/1024) scan stage-1 blocks

// Workspace layout (bytes), total ~58.9 MiB:
#define HB_OFF    0            // h packed bf16: N*64 u32 = 25,600,000
#define AGGB_OFF  25600000     // mean-agg packed bf16: N*64 u32 = 25,600,000
#define WTB_OFF   51200000     // WcatT bf16 B-fragment layout: 16384 u32 = 65,536
#define OFFS_OFF  51265536     // N+1 int (padded to 400,064)
#define BH_OFF    51665600     // NBH ints (padded to 200,704*4 = 802,816)
#define BSUM_OFF  52468416     // HS_BLOCKS ints (padded to 1024)
#define BIN_OFF   52469440     // E ints = 6,400,000 -> end 58,869,440

typedef __attribute__((ext_vector_type(8))) short short8;
typedef __attribute__((ext_vector_type(4))) float floatx4;

// ---------- bf16 pack/unpack (RNE) ----------
__device__ __forceinline__ unsigned bf16pack(float a, float b) {
  unsigned ua = __float_as_uint(a); ua += 0x7fffu + ((ua >> 16) & 1u);
  unsigned ub = __float_as_uint(b); ub += 0x7fffu + ((ub >> 16) & 1u);
  return (ua >> 16) | (ub & 0xffff0000u);
}
__device__ __forceinline__ float2 bf16unpack(unsigned p) {
  return make_float2(__uint_as_float(p << 16), __uint_as_float(p & 0xffff0000u));
}

// ------------- prep: LayerNorm+ReLU -> hb, weight pack (NO atomics) ----------
__global__ __launch_bounds__(256) void k_prep(const float* __restrict__ x,
                                              const float* __restrict__ lw,
                                              const float* __restrict__ lb,
                                              const float* __restrict__ Wl,
                                              const float* __restrict__ Wr,
                                              unsigned* __restrict__ hb,
                                              unsigned* __restrict__ wtb) {
  int gid = blockIdx.x * 256 + threadIdx.x;

  // --- LN+ReLU ---
  {
    int row  = blockIdx.x * 4 + (threadIdx.x >> 6);
    int lane = threadIdx.x & 63;
    float2 v = ((const float2*)(x + (size_t)row * DIM))[lane];
    float s  = v.x + v.y;
    float sq = v.x * v.x + v.y * v.y;
    #pragma unroll
    for (int off = 32; off > 0; off >>= 1) {
      s  += __shfl_xor(s, off);
      sq += __shfl_xor(sq, off);
    }
    float mu  = s * (1.0f / 128.0f);
    float var = sq * (1.0f / 128.0f) - mu * mu;
    float rs  = rsqrtf(var + 1e-5f);
    float2 w = ((const float2*)lw)[lane];
    float2 b = ((const float2*)lb)[lane];
    float ox = fmaxf((v.x - mu) * rs * w.x + b.x, 0.0f);
    float oy = fmaxf((v.y - mu) * rs * w.y + b.y, 0.0f);
    hb[(size_t)row * 64 + lane] = bf16pack(ox, oy);
  }

  // --- weight pack (bf16, B-fragment layout) ---
  if (gid < 16384) {
    int j2 = gid & 3;
    int q  = (gid >> 2) & 3;
    int c  = (gid >> 4) & 127;
    int kb = gid >> 11;
    int k0 = kb * 32 + q * 8 + j2 * 2;
    int k1 = k0 + 1;
    float v0 = (k0 < 128) ? Wl[c * 128 + k0] : Wr[c * 128 + (k0 - 128)];
    float v1 = (k1 < 128) ? Wl[c * 128 + k1] : Wr[c * 128 + (k1 - 128)];
    wtb[gid] = bf16pack(v0, v1);
  }
}

// ---------------- level-1 histogram: coarse bucket = dst>>8 (LDS atomics) ----
__global__ __launch_bounds__(256) void k_hist1(const int* __restrict__ ei,
                                               int* __restrict__ bh) {
  __shared__ int h[NBINS];
  int t = threadIdx.x;
  h[t] = 0; h[t + 256] = 0;
  __syncthreads();
  const int4* d4p = (const int4*)(ei + E_EDGES);
  #pragma unroll
  for (int u = 0; u < 4; ++u) {
    int i4 = blockIdx.x * 1024 + u * 256 + t;
    if (i4 < E_EDGES / 4) {
      int4 d = d4p[i4];
      atomicAdd(&h[d.x >> 8], 1);
      atomicAdd(&h[d.y >> 8], 1);
      atomicAdd(&h[d.z >> 8], 1);
      atomicAdd(&h[d.w >> 8], 1);
    }
  }
  __syncthreads();
  bh[t * NB1 + blockIdx.x] = h[t];
  bh[(t + 256) * NB1 + blockIdx.x] = h[t + 256];
}

// ---------------- scan stage 1 over bh (in-place, 1024 elems/block) ----------
__global__ __launch_bounds__(256) void k_hscan1(int* __restrict__ bh,
                                                int* __restrict__ bsum) {
  __shared__ int s[256];
  int t = threadIdx.x;
  int base = blockIdx.x * 1024 + t * 4;
  int a0 = (base + 0 < NBH) ? bh[base + 0] : 0;
  int a1 = (base + 1 < NBH) ? bh[base + 1] : 0;
  int a2 = (base + 2 < NBH) ? bh[base + 2] : 0;
  int a3 = (base + 3 < NBH) ? bh[base + 3] : 0;
  s[t] = a0 + a1 + a2 + a3;
  __syncthreads();
  #pragma unroll
  for (int off = 1; off < 256; off <<= 1) {
    int x = (t >= off) ? s[t - off] : 0;
    __syncthreads();
    s[t] += x;
    __syncthreads();
  }
  int excl = (t > 0) ? s[t - 1] : 0;
  if (t == 255) bsum[blockIdx.x] = s[255];
  if (base + 0 < NBH) bh[base + 0] = excl;
  if (base + 1 < NBH) bh[base + 1] = excl + a0;
  if (base + 2 < NBH) bh[base + 2] = excl + a0 + a1;
  if (base + 3 < NBH) bh[base + 3] = excl + a0 + a1 + a2;
}

// ---------------- scan stage 2: add block bases (196 <= 256 lanes) -----------
__global__ __launch_bounds__(256) void k_hscan2(int* __restrict__ bh,
                                                const int* __restrict__ bsum) {
  __shared__ int s[256];
  int t = threadIdx.x;
  s[t] = (t < HS_BLOCKS) ? bsum[t] : 0;
  __syncthreads();
  #pragma unroll
  for (int off = 1; off < 256; off <<= 1) {
    int x = (t >= off) ? s[t - off] : 0;
    __syncthreads();
    s[t] += x;
    __syncthreads();
  }
  int blk = blockIdx.x;
  int add = (blk > 0) ? s[blk - 1] : 0;
  #pragma unroll
  for (int u = 0; u < 4; ++u) {
    int i = blk * 1024 + t * 4 + u;
    if (i < NBH) bh[i] += add;
  }
}

// ---------------- level-1 scatter: edges -> coarse buckets (LDS cursors) -----
// packed = src | (dst&255)<<20 ; position from per-(bin,block) scanned base.
__global__ __launch_bounds__(256) void k_scatter1(const int* __restrict__ ei,
                                                  const int* __restrict__ bh,
                                                  int* __restrict__ binned) {
  __shared__ int cur[NBINS];
  int t = threadIdx.x;
  cur[t] = bh[t * NB1 + blockIdx.x];
  cur[t + 256] = bh[(t + 256) * NB1 + blockIdx.x];
  __syncthreads();
  const int4* s4p = (const int4*)ei;
  const int4* d4p = (const int4*)(ei + E_EDGES);
  #pragma unroll
  for (int u = 0; u < 4; ++u) {
    int i4 = blockIdx.x * 1024 + u * 256 + t;
    if (i4 < E_EDGES / 4) {
      int4 sv = s4p[i4];
      int4 dv = d4p[i4];
      int p0 = atomicAdd(&cur[dv.x >> 8], 1);
      int p1 = atomicAdd(&cur[dv.y >> 8], 1);
      int p2 = atomicAdd(&cur[dv.z >> 8], 1);
      int p3 = atomicAdd(&cur[dv.w >> 8], 1);
      binned[p0] = sv.x | ((dv.x & 255) << 20);
      binned[p1] = sv.y | ((dv.y & 255) << 20);
      binned[p2] = sv.z | ((dv.z & 255) << 20);
      binned[p3] = sv.w | ((dv.w & 255) << 20);
    }
  }
}

// ---------------- level-2: per-bucket exact CSR (one block per bucket) -------
__global__ __launch_bounds__(256) void k_csr(const int* __restrict__ bh,
                                             const int* __restrict__ binned,
                                             int* __restrict__ offs,
                                             int* __restrict__ srcidx) {
  __shared__ int h[256];
  __shared__ int s[256];
  __shared__ int cur[256];
  int t = threadIdx.x;
  int bin = blockIdx.x;
  int base = bh[bin * NB1];
  int end  = bh[(bin + 1) * NB1];
  h[t] = 0;
  __syncthreads();
  for (int i = base + t; i < end; i += 256)
    atomicAdd(&h[(binned[i] >> 20) & 255], 1);
  __syncthreads();
  s[t] = h[t];
  __syncthreads();
  #pragma unroll
  for (int off = 1; off < 256; off <<= 1) {
    int x = (t >= off) ? s[t - off] : 0;
    __syncthreads();
    s[t] += x;
    __syncthreads();
  }
  int excl = (t > 0) ? s[t - 1] : 0;
  cur[t] = excl;
  int node = bin * 256 + t;
  if (node < N_NODES) offs[node] = base + excl;
  if (node == N_NODES) offs[N_NODES] = E_EDGES;
  __syncthreads();
  for (int i = base + t; i < end; i += 256) {
    int p = binned[i];
    int r = atomicAdd(&cur[(p >> 20) & 255], 1);
    srcidx[base + r] = p & 0xFFFFF;
  }
}

// ---------------- gather + mean -> aggb (bf16) -------------------------------
// TWO nodes per wave with interleaved load chains -> 16 outstanding 256B row
// loads per wave. Still 50K independent waves (TLP matters).
__global__ __launch_bounds__(256) void k_gather(const unsigned* __restrict__ hb,
                                                const int* __restrict__ offs,
                                                const int* __restrict__ srcidx,
                                                unsigned* __restrict__ aggb) {
  int wave = threadIdx.x >> 6;
  int lane = threadIdx.x & 63;
  int n0 = blockIdx.x * 8 + wave * 2;
  int n1 = n0 + 1;
  int b0 = __builtin_amdgcn_readfirstlane(offs[n0]);
  int e0 = __builtin_amdgcn_readfirstlane(offs[n0 + 1]);
  int b1 = __builtin_amdgcn_readfirstlane(offs[n1]);
  int e1 = __builtin_amdgcn_readfirstlane(offs[n1 + 1]);
  int m0 = e0 - b0, m1 = e1 - b1;
  int c  = (m0 < m1 ? m0 : m1) & ~7;   // common interleaved part

  float ax0 = 0.0f, ay0 = 0.0f, ax1 = 0.0f, ay1 = 0.0f;

  // interleaved: 16 outstanding loads (8 per chain)
  for (int j = 0; j < c; j += 8) {
    unsigned p0[8], p1[8];
    #pragma unroll
    for (int i = 0; i < 8; ++i) {
      int s0 = srcidx[b0 + j + i];
      int s1 = srcidx[b1 + j + i];
      p0[i] = hb[(size_t)s0 * 64 + lane];
      p1[i] = hb[(size_t)s1 * 64 + lane];
    }
    #pragma unroll
    for (int i = 0; i < 8; ++i) {
      float2 v0 = bf16unpack(p0[i]);
      float2 v1 = bf16unpack(p1[i]);
      ax0 += v0.x; ay0 += v0.y;
      ax1 += v1.x; ay1 += v1.y;
    }
  }
  // tail of node 0
  for (int j = b0 + c; j < e0; ) {
    int rem = e0 - j;
    if (rem >= 8) {
      unsigned p[8];
      #pragma unroll
      for (int i = 0; i < 8; ++i) p[i] = hb[(size_t)srcidx[j + i] * 64 + lane];
      #pragma unroll
      for (int i = 0; i < 8; ++i) { float2 v = bf16unpack(p[i]); ax0 += v.x; ay0 += v.y; }
      j += 8;
    } else {
      float2 v = bf16unpack(hb[(size_t)srcidx[j] * 64 + lane]);
      ax0 += v.x; ay0 += v.y;
      ++j;
    }
  }
  // tail of node 1
  for (int j = b1 + c; j < e1; ) {
    int rem = e1 - j;
    if (rem >= 8) {
      unsigned p[8];
      #pragma unroll
      for (int i = 0; i < 8; ++i) p[i] = hb[(size_t)srcidx[j + i] * 64 + lane];
      #pragma unroll
      for (int i = 0; i < 8; ++i) { float2 v = bf16unpack(p[i]); ax1 += v.x; ay1 += v.y; }
      j += 8;
    } else {
      float2 v = bf16unpack(hb[(size_t)srcidx[j] * 64 + lane]);
      ax1 += v.x; ay1 += v.y;
      ++j;
    }
  }

  float inv0 = 1.0f / fmaxf((float)m0, 1.0f);
  float inv1 = 1.0f / fmaxf((float)m1, 1.0f);
  aggb[(size_t)n0 * 64 + lane] = bf16pack(ax0 * inv0, ay0 * inv0);
  aggb[(size_t)n1 * 64 + lane] = bf16pack(ax1 * inv1, ay1 * inv1);
}

// ---------------- bf16 MFMA GEMM: out = [aggb|hb] @ WcatT^T + b_l ------------
__global__ __launch_bounds__(256) void k_gemm(const unsigned* __restrict__ aggb,
                                              const unsigned* __restrict__ hb,
                                              const unsigned* __restrict__ wtb,
                                              const float* __restrict__ bl,
                                              float* __restrict__ out) {
  int wave = threadIdx.x >> 6;
  int lane = threadIdx.x & 63;
  int m = lane & 15;
  int q = lane >> 4;
  int r0 = blockIdx.x * 64 + wave * 16;
  int rowA = r0 + m;
  if (rowA > N_NODES - 1) rowA = N_NODES - 1;  // tail clamp (stores guarded)

  const uint4* ar = (const uint4*)(aggb + (size_t)rowA * 64);
  const uint4* hr = (const uint4*)(hb + (size_t)rowA * 64);
  short8 afrag[8];
  #pragma unroll
  for (int kb = 0; kb < 4; ++kb) {
    uint4 u = ar[kb * 4 + q];
    afrag[kb] = *(short8*)&u;
  }
  #pragma unroll
  for (int kb = 0; kb < 4; ++kb) {
    uint4 u = hr[kb * 4 + q];
    afrag[kb + 4] = *(short8*)&u;
  }

  const uint4* b4 = (const uint4*)wtb;
  #pragma unroll
  for (int ct = 0; ct < 8; ++ct) {
    int c = ct * 16 + m;
    floatx4 acc = {0.0f, 0.0f, 0.0f, 0.0f};
    #pragma unroll
    for (int kb = 0; kb < 8; ++kb) {
      uint4 u = b4[kb * 512 + c * 4 + q];
      short8 bfrag = *(short8*)&u;
      acc = __builtin_amdgcn_mfma_f32_16x16x32_bf16(afrag[kb], bfrag, acc, 0, 0, 0);
    }
    float bias = bl[c];
    #pragma unroll
    for (int reg = 0; reg < 4; ++reg) {
      int r = r0 + q * 4 + reg;
      if (r < N_NODES) out[(size_t)r * DIM + c] = acc[reg] + bias;
    }
  }
}

extern "C" void kernel_launch(void* const* d_in, const int* in_sizes, int n_in,
                              void* d_out, int out_size, void* d_ws, size_t ws_size,
                              hipStream_t stream) {
  const float* x  = (const float*)d_in[0];
  const int*   ei = (const int*)d_in[1];   // [2, E] int32
  const float* lw = (const float*)d_in[2];
  const float* lb = (const float*)d_in[3];
  const float* Wl = (const float*)d_in[4];
  const float* bl = (const float*)d_in[5];
  const float* Wr = (const float*)d_in[6];
  float* out = (float*)d_out;

  char* ws = (char*)d_ws;
  unsigned* hb     = (unsigned*)(ws + HB_OFF);
  unsigned* aggb   = (unsigned*)(ws + AGGB_OFF);
  unsigned* wtb    = (unsigned*)(ws + WTB_OFF);
  int*      offs   = (int*)(ws + OFFS_OFF);
  int*      bh     = (int*)(ws + BH_OFF);
  int*      bsum   = (int*)(ws + BSUM_OFF);
  int*      binned = (int*)(ws + BIN_OFF);
  int*      srcidx = binned;  // NOT aliased in time: srcidx written in k_csr after
                              // binned is consumed? NO — k_csr reads binned twice
                              // then writes srcidx. Keep them separate:
  srcidx = (int*)(ws + BIN_OFF);  // placeholder, fixed below

  // separate srcidx region right after binned:
  srcidx = (int*)(ws + BIN_OFF + (size_t)E_EDGES * 4);  // 58,869,440 .. 65,269,440

  k_prep<<<N_NODES / 4, 256, 0, stream>>>(x, lw, lb, Wl, Wr, hb, wtb);
  k_hist1<<<NB1, 256, 0, stream>>>(ei, bh);
  k_hscan1<<<HS_BLOCKS, 256, 0, stream>>>(bh, bsum);
  k_hscan2<<<HS_BLOCKS, 256, 0, stream>>>(bh, bsum);
  k_scatter1<<<NB1, 256, 0, stream>>>(ei, bh, binned);
  k_csr<<<NB1, 256, 0, stream>>>(bh, binned, offs, srcidx);
  k_gather<<<N_NODES / 8, 256, 0, stream>>>(hb, offs, srcidx, aggb);
  k_gemm<<<(N_NODES + 63) / 64, 256, 0, stream>>>(aggb, hb, wtb, bl, out);
}